// Round 2
// baseline (740.976 us; speedup 1.0000x reference)
//
#include <hip/hip_runtime.h>

typedef unsigned short u16;
typedef unsigned int u32;

using short8 = __attribute__((ext_vector_type(8))) short;
using f32x4  = __attribute__((ext_vector_type(4))) float;

#define LOG2E 1.44269504088896340736f

// X1 row: [h1_hi 0:128 | h1_lo 128:256 | x 256:272 | zero-pad 272:288 | unused]
#define X1S 296
// H2 row: [h2_hi 0:64 | h2_lo 64:128 | pad]
#define H2S 136
#define DBS 40

__device__ __forceinline__ u16 f2bf(float f) {
  u32 u = __float_as_uint(f);
  return (u16)((u + 0x7FFFu + ((u >> 16) & 1u)) >> 16);
}
__device__ __forceinline__ float bf2f(u16 h) {
  return __uint_as_float(((u32)h) << 16);
}
__device__ __forceinline__ float sigm(float x) {
  return __builtin_amdgcn_rcpf(1.0f + __builtin_amdgcn_exp2f(-LOG2E * x));
}
__device__ __forceinline__ float tanh_(float x) {
  return 1.0f - 2.0f * __builtin_amdgcn_rcpf(1.0f + __builtin_amdgcn_exp2f(2.0f * LOG2E * x));
}
__device__ __forceinline__ f32x4 mfma_(short8 a, short8 b, f32x4 c) {
  return __builtin_amdgcn_mfma_f32_16x16x32_bf16(a, b, c, 0, 0, 0);
}

__global__ __launch_bounds__(256, 1) void spc_lstm(
    const float* __restrict__ xh,   const float* __restrict__ xfr,
    const float* __restrict__ Wih1, const float* __restrict__ Whh1,
    const float* __restrict__ bih1, const float* __restrict__ bhh1,
    const float* __restrict__ Wih2, const float* __restrict__ Whh2,
    const float* __restrict__ bih2, const float* __restrict__ bhh2,
    const float* __restrict__ Wd,   const float* __restrict__ bd,
    const float* __restrict__ Wf,   const float* __restrict__ bfv,
    const float* __restrict__ ob,   float* __restrict__ out)
{
  __shared__ __align__(16) u16 X1[2][16 * X1S];
  __shared__ __align__(16) u16 H2B[2][16 * H2S];
  __shared__ __align__(16) u16 DB[16 * DBS];
  __shared__ u16 PREDV[16][2];   // accessed via volatile pointers

  const int tid = threadIdx.x;
  const int w   = tid >> 6;   // wave 0..3
  const int l   = tid & 63;
  const int c   = l & 15;     // MFMA col / A-row (= batch for A-loads)
  const int q   = l >> 4;     // quarter
  const int bb  = blockIdx.x << 4;

  // ---------------- persistent weight fragments (registers) ----------------
  short8 w1[8][5];   // L1: [ntile][k-chunk 0..3 = Whh1, 4 = Wih1(x)]
  short8 w2[4][6];   // L2: [gate-group][0..3 = Wih2 (h1), 4..5 = Whh2 (h2)]
  short8 wdf[2];     // waves 0,1: Wd k-chunks
  short8 wff;        // wave 0: Wf (cols >=2 zero)
  float  b1r[8], b2r[4], bdr = 0.f, bfr = 0.f;

  #pragma unroll
  for (int nt = 0; nt < 8; nt++) {
    const int g = (nt >> 1) * 128 + w * 32 + (nt & 1) * 16 + c;  // i,f,g,o order
    b1r[nt] = bih1[g] + bhh1[g];
    #pragma unroll
    for (int kc = 0; kc < 4; kc++) {
      short8 v;
      #pragma unroll
      for (int j = 0; j < 8; j++)
        v[j] = (short)f2bf(Whh1[g * 128 + kc * 32 + q * 8 + j]);
      w1[nt][kc] = v;
    }
    short8 v;
    #pragma unroll
    for (int j = 0; j < 8; j++) {
      int k = q * 8 + j;
      v[j] = (k < 16) ? (short)f2bf(Wih1[g * 16 + k]) : (short)0;
    }
    w1[nt][4] = v;
  }
  #pragma unroll
  for (int nt = 0; nt < 4; nt++) {
    const int g = nt * 64 + w * 16 + c;
    b2r[nt] = bih2[g] + bhh2[g];
    #pragma unroll
    for (int kc = 0; kc < 4; kc++) {
      short8 v;
      #pragma unroll
      for (int j = 0; j < 8; j++)
        v[j] = (short)f2bf(Wih2[g * 128 + kc * 32 + q * 8 + j]);
      w2[nt][kc] = v;
    }
    #pragma unroll
    for (int kc = 0; kc < 2; kc++) {
      short8 v;
      #pragma unroll
      for (int j = 0; j < 8; j++)
        v[j] = (short)f2bf(Whh2[g * 64 + kc * 32 + q * 8 + j]);
      w2[nt][4 + kc] = v;
    }
  }
  if (w < 2) {
    const int g = w * 16 + c;
    bdr = bd[g];
    #pragma unroll
    for (int kc = 0; kc < 2; kc++) {
      short8 v;
      #pragma unroll
      for (int j = 0; j < 8; j++)
        v[j] = (short)f2bf(Wd[g * 64 + kc * 32 + q * 8 + j]);
      wdf[kc] = v;
    }
  }
  if (w == 0) {
    short8 v;
    #pragma unroll
    for (int j = 0; j < 8; j++)
      v[j] = (c < 2) ? (short)f2bf(Wf[c * 32 + q * 8 + j]) : (short)0;
    wff = v;
    bfr = (c < 2) ? (bfv[c] + ob[c]) : 0.f;
  }

  // ---------------- zero ALL LDS ----------------
  for (int i = tid; i < 2 * 16 * X1S; i += 256) ((u16*)X1)[i] = 0;
  for (int i = tid; i < 2 * 16 * H2S; i += 256) ((u16*)H2B)[i] = 0;
  for (int i = tid; i < 16 * DBS; i += 256) DB[i] = 0;

  __syncthreads();  // BUGFIX R1: zero-init must complete before x0 staging

  const int xr  = tid >> 4;   // x-loader geometry: row, feature
  const int xcc = tid & 15;
  // stage x(0)
  X1[0][xr * X1S + 256 + xcc] = f2bf(xh[(bb + xr) * 3200 + xcc]);
  // prime 2-deep prefetch pipeline with x(1)
  float xreg = 0.f; bool dreg = true;
  xreg = xh[(bb + xr) * 3200 + 16 + xcc];

  f32x4 c1[2]; f32x4 c2;
  c1[0] = (f32x4){0,0,0,0}; c1[1] = (f32x4){0,0,0,0}; c2 = (f32x4){0,0,0,0};

  __syncthreads();

  for (int t = 0; t < 220; t++) {
    const int p = t & 1;
    u16* Xc = X1[p];
    u16* Xn = X1[p ^ 1];
    u16* Hc = H2B[p];
    u16* Hn = H2B[p ^ 1];

    // x pipeline: xw = x(t+1) (loaded at step t-1); issue load of x(t+2)
    const float xw = xreg; const bool dw = dreg;
    {
      const int s2 = t + 2;
      dreg = false;
      if (s2 < 200) { xreg = xh[(bb + xr) * 3200 + s2 * 16 + xcc]; dreg = true; }
      else if (s2 < 220) {
        const int s = s2 - 200;
        if (xcc < 14)    { xreg = xfr[(bb + xr) * 280 + s * 14 + xcc]; dreg = true; }
        else if (s == 0) { xreg = xh[(bb + xr) * 3200 + 199 * 16 + xcc]; dreg = true; }
        // s>0, xcc>=14: pred feedback (PREDV patch)
      }
    }

    // ---- L1 A-fragments: [h_hi x4 | h_lo x4 | x] ----
    short8 a[9];
    #pragma unroll
    for (int kc = 0; kc < 9; kc++)
      a[kc] = *(const short8*)&Xc[c * X1S + kc * 32 + q * 8];

    // decoder steps s>=1: authoritative pred feedback via volatile PREDV,
    // patched straight into the register fragment (x feats 14,15 = q==1, j=6,7)
    if (t >= 201 && q == 1) {
      volatile const u16* pv = &PREDV[0][0];
      a[8][6] = (short)pv[c * 2 + 0];
      a[8][7] = (short)pv[c * 2 + 1];
    }

    // stage x(t+1) into Xn for consumption at t+1
    if (dw) Xn[xr * X1S + 256 + xcc] = f2bf(xw);

    // ---- L1 MFMA (hi + lo reuse identical weight frags) ----
    f32x4 acc[8];
    #pragma unroll
    for (int nt = 0; nt < 8; nt++)
      acc[nt] = (f32x4){b1r[nt], b1r[nt], b1r[nt], b1r[nt]};
    #pragma unroll
    for (int nt = 0; nt < 8; nt++) {
      #pragma unroll
      for (int kc = 0; kc < 4; kc++) {
        acc[nt] = mfma_(a[kc],     w1[nt][kc], acc[nt]);
        acc[nt] = mfma_(a[4 + kc], w1[nt][kc], acc[nt]);
      }
      acc[nt] = mfma_(a[8], w1[nt][4], acc[nt]);
    }

    // ---- L1 cell update + h1 hi/lo write ----
    #pragma unroll
    for (int sub = 0; sub < 2; sub++) {
      const int u = w * 32 + sub * 16 + c;
      #pragma unroll
      for (int r = 0; r < 4; r++) {
        float ig = sigm(acc[sub][r]);
        float fg = sigm(acc[2 + sub][r]);
        float gg = tanh_(acc[4 + sub][r]);
        float og = sigm(acc[6 + sub][r]);
        float cn = fg * c1[sub][r] + ig * gg;
        float hn = og * tanh_(cn);
        c1[sub][r] = cn;
        u16 hi = f2bf(hn);
        float lo = hn - bf2f(hi);
        const int row = (q * 4 + r) * X1S;
        Xn[row + u]       = hi;
        Xn[row + 128 + u] = f2bf(lo);
      }
    }

    __syncthreads();  // h1_t visible

    // ---- L2: A = [h1_t (from Xn) | h2_{t-1} (from Hc)] ----
    short8 a2[12];
    #pragma unroll
    for (int kc = 0; kc < 8; kc++)
      a2[kc] = *(const short8*)&Xn[c * X1S + kc * 32 + q * 8];
    #pragma unroll
    for (int kc = 0; kc < 4; kc++)
      a2[8 + kc] = *(const short8*)&Hc[c * H2S + kc * 32 + q * 8];

    f32x4 acc2[4];
    #pragma unroll
    for (int nt = 0; nt < 4; nt++)
      acc2[nt] = (f32x4){b2r[nt], b2r[nt], b2r[nt], b2r[nt]};
    #pragma unroll
    for (int nt = 0; nt < 4; nt++) {
      #pragma unroll
      for (int kc = 0; kc < 4; kc++) {
        acc2[nt] = mfma_(a2[kc],     w2[nt][kc], acc2[nt]);
        acc2[nt] = mfma_(a2[4 + kc], w2[nt][kc], acc2[nt]);
      }
      #pragma unroll
      for (int kc = 0; kc < 2; kc++) {
        acc2[nt] = mfma_(a2[8 + kc],  w2[nt][4 + kc], acc2[nt]);
        acc2[nt] = mfma_(a2[10 + kc], w2[nt][4 + kc], acc2[nt]);
      }
    }

    // ---- L2 cell update + h2 hi/lo write ----
    {
      const int u = w * 16 + c;
      #pragma unroll
      for (int r = 0; r < 4; r++) {
        float ig = sigm(acc2[0][r]);
        float fg = sigm(acc2[1][r]);
        float gg = tanh_(acc2[2][r]);
        float og = sigm(acc2[3][r]);
        float cn = fg * c2[r] + ig * gg;
        float hn = og * tanh_(cn);
        c2[r] = cn;
        u16 hi = f2bf(hn);
        float lo = hn - bf2f(hi);
        const int row = (q * 4 + r) * H2S;
        Hn[row + u]      = hi;
        Hn[row + 64 + u] = f2bf(lo);
      }
    }

    // ---- decoder head (barriers unconditional every step) ----
    __syncthreads();  // h2_t visible
    if (t >= 200 && w < 2) {
      short8 ad[4];
      #pragma unroll
      for (int kc = 0; kc < 4; kc++)
        ad[kc] = *(const short8*)&Hn[c * H2S + kc * 32 + q * 8];
      f32x4 accd = (f32x4){bdr, bdr, bdr, bdr};
      accd = mfma_(ad[0], wdf[0], accd);
      accd = mfma_(ad[1], wdf[1], accd);
      accd = mfma_(ad[2], wdf[0], accd);
      accd = mfma_(ad[3], wdf[1], accd);
      #pragma unroll
      for (int r = 0; r < 4; r++) {
        float dv = fmaxf(accd[r], 0.f);
        DB[(q * 4 + r) * DBS + w * 16 + c] = f2bf(dv);
      }
    }
    __syncthreads();  // d visible
    if (t >= 200 && w == 0) {
      short8 ap = *(const short8*)&DB[c * DBS + q * 8];
      f32x4 accp = (f32x4){bfr, bfr, bfr, bfr};
      accp = mfma_(ap, wff, accp);
      if (c < 2) {
        volatile u16* pv = &PREDV[0][0];
        #pragma unroll
        for (int r = 0; r < 4; r++) {
          const int b = q * 4 + r;
          out[(bb + b) * 40 + (t - 200) * 2 + c] = accp[r];
          pv[b * 2 + c] = f2bf(accp[r]);   // feedback for step t+1
        }
      }
    }
    __syncthreads();  // end-of-step
  }
}

extern "C" void kernel_launch(void* const* d_in, const int* in_sizes, int n_in,
                              void* d_out, int out_size, void* d_ws, size_t ws_size,
                              hipStream_t stream) {
  (void)in_sizes; (void)n_in; (void)out_size; (void)d_ws; (void)ws_size;
  spc_lstm<<<dim3(256), dim3(256), 0, stream>>>(
      (const float*)d_in[0],  (const float*)d_in[1],
      (const float*)d_in[2],  (const float*)d_in[3],
      (const float*)d_in[4],  (const float*)d_in[5],
      (const float*)d_in[6],  (const float*)d_in[7],
      (const float*)d_in[8],  (const float*)d_in[9],
      (const float*)d_in[10], (const float*)d_in[11],
      (const float*)d_in[12], (const float*)d_in[13],
      (const float*)d_in[14], (float*)d_out);
}